// Round 1
// baseline (176.294 us; speedup 1.0000x reference)
//
#include <hip/hip_runtime.h>

#define VOCAB 100000
#define HALF  256      // HIDDEN/2
#define NC    256      // NUM_CLUSTERS
#define NTOK  16384    // B*S
#define TPB   16       // tokens per block
#define DSTR  264      // padded dist stride (dwords) to spread LDS banks

__global__ __launch_bounds__(512)
void hle_fused(const int*   __restrict__ ids,
               const float* __restrict__ fine_w,     // [VOCAB, HALF]
               const float* __restrict__ coarse_w,   // [NC, HALF]
               const float* __restrict__ cluster_w,  // [NC, VOCAB]
               const float* __restrict__ cluster_b,  // [NC]
               float*       __restrict__ out)        // [NTOK, 512]
{
    __shared__ float dist[TPB][DSTR];

    const int tid  = threadIdx.x;
    const int wave = tid >> 6;   // 0..7
    const int lane = tid & 63;
    const int base = blockIdx.x * TPB;

    // ---------------- Phase 1: logits gather + softmax + fine gather ----------------
    // Each wave handles tokens (wave) and (wave+8). Issue ALL global loads first
    // so the scattered column-gather loads overlap (16 in flight per wave).
    {
        const int tokA = base + wave;
        const int tokB = base + wave + 8;
        const int idA = ids[tokA];
        const int idB = ids[tokB];

        // fine rows: 64 lanes x float4 = 256 f32 (coalesced 1KB)
        const float4 fA = *reinterpret_cast<const float4*>(fine_w + (size_t)idA * HALF + lane * 4);
        const float4 fB = *reinterpret_cast<const float4*>(fine_w + (size_t)idB * HALF + lane * 4);

        // scattered logit loads: cluster c = lane + 64k, column id
        float lA[4], lB[4];
#pragma unroll
        for (int k = 0; k < 4; ++k) {
            const int c = lane + 64 * k;
            lA[k] = cluster_w[(size_t)c * VOCAB + idA];
            lB[k] = cluster_w[(size_t)c * VOCAB + idB];
        }

#pragma unroll
        for (int k = 0; k < 4; ++k) {
            const int c = lane + 64 * k;
            const float b = cluster_b[c];
            lA[k] += b;
            lB[k] += b;
        }

        // write fine halves while softmax math proceeds
        *reinterpret_cast<float4*>(out + (size_t)tokA * 512 + lane * 4) = fA;
        *reinterpret_cast<float4*>(out + (size_t)tokB * 512 + lane * 4) = fB;

        // ---- softmax token A ----
        {
            float m = fmaxf(fmaxf(lA[0], lA[1]), fmaxf(lA[2], lA[3]));
#pragma unroll
            for (int off = 32; off >= 1; off >>= 1) m = fmaxf(m, __shfl_xor(m, off));
            float e[4], s = 0.f;
#pragma unroll
            for (int k = 0; k < 4; ++k) { e[k] = __expf(lA[k] - m); s += e[k]; }
#pragma unroll
            for (int off = 32; off >= 1; off >>= 1) s += __shfl_xor(s, off);
            const float inv = 1.f / s;
#pragma unroll
            for (int k = 0; k < 4; ++k) dist[wave][lane + 64 * k] = e[k] * inv;
        }
        // ---- softmax token B ----
        {
            float m = fmaxf(fmaxf(lB[0], lB[1]), fmaxf(lB[2], lB[3]));
#pragma unroll
            for (int off = 32; off >= 1; off >>= 1) m = fmaxf(m, __shfl_xor(m, off));
            float e[4], s = 0.f;
#pragma unroll
            for (int k = 0; k < 4; ++k) { e[k] = __expf(lB[k] - m); s += e[k]; }
#pragma unroll
            for (int off = 32; off >= 1; off >>= 1) s += __shfl_xor(s, off);
            const float inv = 1.f / s;
#pragma unroll
            for (int k = 0; k < 4; ++k) dist[wave + 8][lane + 64 * k] = e[k] * inv;
        }
    }

    __syncthreads();

    // ---------------- Phase 2: coarse mixture (mat-vec per token) ----------------
    // thread = (token t, column group hg); each thread computes 8 outputs.
    {
        const int t  = tid >> 5;        // 0..15
        const int hg = tid & 31;        // 0..31 -> columns hg*8 .. hg*8+7
        const int token = base + t;

        float acc[8] = {0.f, 0.f, 0.f, 0.f, 0.f, 0.f, 0.f, 0.f};
        const float* cw = coarse_w + hg * 8;

#pragma unroll 4
        for (int c = 0; c < NC; ++c) {
            const float e = dist[t][c];
            const float4 v0 = *reinterpret_cast<const float4*>(cw + c * HALF);
            const float4 v1 = *reinterpret_cast<const float4*>(cw + c * HALF + 4);
            acc[0] = fmaf(e, v0.x, acc[0]);
            acc[1] = fmaf(e, v0.y, acc[1]);
            acc[2] = fmaf(e, v0.z, acc[2]);
            acc[3] = fmaf(e, v0.w, acc[3]);
            acc[4] = fmaf(e, v1.x, acc[4]);
            acc[5] = fmaf(e, v1.y, acc[5]);
            acc[6] = fmaf(e, v1.z, acc[6]);
            acc[7] = fmaf(e, v1.w, acc[7]);
        }

        float* o = out + (size_t)token * 512 + 256 + hg * 8;
        *reinterpret_cast<float4*>(o)     = make_float4(acc[0], acc[1], acc[2], acc[3]);
        *reinterpret_cast<float4*>(o + 4) = make_float4(acc[4], acc[5], acc[6], acc[7]);
    }
}

extern "C" void kernel_launch(void* const* d_in, const int* in_sizes, int n_in,
                              void* d_out, int out_size, void* d_ws, size_t ws_size,
                              hipStream_t stream) {
    const int*   ids       = (const int*)  d_in[0];
    const float* fine_w    = (const float*)d_in[1];
    const float* coarse_w  = (const float*)d_in[2];
    const float* cluster_w = (const float*)d_in[3];
    const float* cluster_b = (const float*)d_in[4];
    float*       out       = (float*)d_out;

    hipLaunchKernelGGL(hle_fused, dim3(NTOK / TPB), dim3(512), 0, stream,
                       ids, fine_w, coarse_w, cluster_w, cluster_b, out);
}

// Round 2
// 108.281 us; speedup vs baseline: 1.6281x; 1.6281x over previous
//
#include <hip/hip_runtime.h>

#define VOCAB 100000
#define HALF  256      // HIDDEN/2
#define NC    256      // NUM_CLUSTERS
#define NTOK  16384    // B*S
#define TPB   32       // tokens per block
#define CK    32       // cluster rows staged per chunk

// LDS: distT 256x32 f32 = 32 KB (+swizzle), cw_tile 32x256 f32 = 32 KB -> 64 KB -> 2 blocks/CU
__global__ __launch_bounds__(512, 4)
void hle_fused(const int*   __restrict__ ids,
               const float* __restrict__ fine_w,     // [VOCAB, HALF]
               const float* __restrict__ coarse_w,   // [NC, HALF]
               const float* __restrict__ cluster_w,  // [NC, VOCAB]
               const float* __restrict__ cluster_b,  // [NC]
               float*       __restrict__ out)        // [NTOK, 512]
{
    __shared__ float distT[NC][TPB];     // value for token t stored at distT[c][t ^ (c&28)]
    __shared__ float cw_tile[CK][HALF];

    const int tid  = threadIdx.x;
    const int wave = tid >> 6;   // 0..7
    const int lane = tid & 63;
    const int base = blockIdx.x * TPB;

    // ---------------- Phase 1: logits gather + softmax + fine gather ----------------
    // wave handles local tokens wave*4 .. wave*4+3; all scattered loads issued up front
    {
        const int t0 = wave * 4;
        int id[4];
#pragma unroll
        for (int i = 0; i < 4; ++i) id[i] = ids[base + t0 + i];

        // fine rows: 64 lanes x float4 (coalesced 1KB per token)
        float4 f[4];
#pragma unroll
        for (int i = 0; i < 4; ++i)
            f[i] = *reinterpret_cast<const float4*>(fine_w + (size_t)id[i] * HALF + lane * 4);

        // scattered logit gather: 16 loads in flight per lane
        float lg[4][4];
#pragma unroll
        for (int i = 0; i < 4; ++i)
#pragma unroll
            for (int k = 0; k < 4; ++k)
                lg[i][k] = cluster_w[(size_t)(lane + 64 * k) * VOCAB + id[i]];

        float bias[4];
#pragma unroll
        for (int k = 0; k < 4; ++k) bias[k] = cluster_b[lane + 64 * k];

#pragma unroll
        for (int i = 0; i < 4; ++i) {
#pragma unroll
            for (int k = 0; k < 4; ++k) lg[i][k] += bias[k];

            float m = fmaxf(fmaxf(lg[i][0], lg[i][1]), fmaxf(lg[i][2], lg[i][3]));
#pragma unroll
            for (int off = 32; off >= 1; off >>= 1) m = fmaxf(m, __shfl_xor(m, off));
            float e[4], s = 0.f;
#pragma unroll
            for (int k = 0; k < 4; ++k) { e[k] = __expf(lg[i][k] - m); s += e[k]; }
#pragma unroll
            for (int off = 32; off >= 1; off >>= 1) s += __shfl_xor(s, off);
            const float inv = 1.f / s;

            const int t = t0 + i;
#pragma unroll
            for (int k = 0; k < 4; ++k) {
                const int c = lane + 64 * k;
                distT[c][t ^ (c & 28)] = e[k] * inv;   // 8-way conflict, 16 writes/wave total
            }
            // fine half of output
            *reinterpret_cast<float4*>(out + (size_t)(base + t) * 512 + lane * 4) = f[i];
        }
    }

    // ---------------- Phase 2: coarse mixture, LDS-staged coarse_w ----------------
    // thread = (wave -> tokens wave*4..+3, lane -> cols lane*4..+3), acc[4][4]
    float acc[4][4] = {{0.f}};
    const int tg4 = wave * 4;
    const int colbase = lane * 4;

    for (int ch = 0; ch < NC / CK; ++ch) {
        __syncthreads();   // prev chunk consumed (and, at ch=0, distT written)
        {
            // stage CK x 256 f32 chunk, coalesced float4 copy (4 per thread)
            const float4* src = reinterpret_cast<const float4*>(coarse_w + (size_t)ch * CK * HALF);
            float4* dst = reinterpret_cast<float4*>(&cw_tile[0][0]);
#pragma unroll
            for (int p = 0; p < 4; ++p)
                dst[tid + p * 512] = src[tid + p * 512];
        }
        __syncthreads();   // chunk ready

#pragma unroll 8
        for (int j = 0; j < CK; ++j) {
            const int cc = ch * CK + j;
            const float4 d = *reinterpret_cast<const float4*>(&distT[cc][tg4 ^ (cc & 28)]); // broadcast
            const float4 v = *reinterpret_cast<const float4*>(&cw_tile[j][colbase]);        // contiguous
            acc[0][0] = fmaf(d.x, v.x, acc[0][0]);
            acc[0][1] = fmaf(d.x, v.y, acc[0][1]);
            acc[0][2] = fmaf(d.x, v.z, acc[0][2]);
            acc[0][3] = fmaf(d.x, v.w, acc[0][3]);
            acc[1][0] = fmaf(d.y, v.x, acc[1][0]);
            acc[1][1] = fmaf(d.y, v.y, acc[1][1]);
            acc[1][2] = fmaf(d.y, v.z, acc[1][2]);
            acc[1][3] = fmaf(d.y, v.w, acc[1][3]);
            acc[2][0] = fmaf(d.z, v.x, acc[2][0]);
            acc[2][1] = fmaf(d.z, v.y, acc[2][1]);
            acc[2][2] = fmaf(d.z, v.z, acc[2][2]);
            acc[2][3] = fmaf(d.z, v.w, acc[2][3]);
            acc[3][0] = fmaf(d.w, v.x, acc[3][0]);
            acc[3][1] = fmaf(d.w, v.y, acc[3][1]);
            acc[3][2] = fmaf(d.w, v.z, acc[3][2]);
            acc[3][3] = fmaf(d.w, v.w, acc[3][3]);
        }
    }

    // epilogue: coarse half of output, one float4 per token row
#pragma unroll
    for (int jj = 0; jj < 4; ++jj) {
        float* o = out + (size_t)(base + tg4 + jj) * 512 + 256 + colbase;
        *reinterpret_cast<float4*>(o) = make_float4(acc[jj][0], acc[jj][1], acc[jj][2], acc[jj][3]);
    }
}

extern "C" void kernel_launch(void* const* d_in, const int* in_sizes, int n_in,
                              void* d_out, int out_size, void* d_ws, size_t ws_size,
                              hipStream_t stream) {
    const int*   ids       = (const int*)  d_in[0];
    const float* fine_w    = (const float*)d_in[1];
    const float* coarse_w  = (const float*)d_in[2];
    const float* cluster_w = (const float*)d_in[3];
    const float* cluster_b = (const float*)d_in[4];
    float*       out       = (float*)d_out;

    hipLaunchKernelGGL(hle_fused, dim3(NTOK / TPB), dim3(512), 0, stream,
                       ids, fine_w, coarse_w, cluster_w, cluster_b, out);
}

// Round 3
// 81.435 us; speedup vs baseline: 2.1649x; 1.3297x over previous
//
#include <hip/hip_runtime.h>

#define VOCAB 100000
#define HALF  256      // HIDDEN/2
#define NC    256      // NUM_CLUSTERS
#define NTOK  16384    // B*S
#define TPB   32       // tokens per block
#define CK    32       // cluster rows staged per chunk
#define NBUCK 2048     // id>>6 -> 0..1562, padded to 2048

// ---------------- sort prework ----------------
__global__ __launch_bounds__(1024)
void hist_kernel(const int* __restrict__ ids, int* __restrict__ hist) {
    const int t = blockIdx.x * 1024 + threadIdx.x;   // grid 16x1024 == NTOK
    atomicAdd(&hist[ids[t] >> 6], 1);
}

__global__ __launch_bounds__(1024)
void scan_kernel(const int* __restrict__ hist, int* __restrict__ offs) {
    __shared__ int part[1024];
    const int tid = threadIdx.x;
    const int h0 = hist[2 * tid], h1 = hist[2 * tid + 1];
    part[tid] = h0 + h1;
    __syncthreads();
    for (int off = 1; off < 1024; off <<= 1) {
        const int v   = part[tid];
        const int add = (tid >= off) ? part[tid - off] : 0;
        __syncthreads();
        part[tid] = v + add;
        __syncthreads();
    }
    const int excl = (tid == 0) ? 0 : part[tid - 1];
    offs[2 * tid]     = excl;
    offs[2 * tid + 1] = excl + h0;
}

__global__ __launch_bounds__(1024)
void scatter_kernel(const int* __restrict__ ids, int* __restrict__ offs,
                    int* __restrict__ sorted) {
    const int t = blockIdx.x * 1024 + threadIdx.x;
    const int pos = atomicAdd(&offs[ids[t] >> 6], 1);
    sorted[pos] = t;
}

// ---------------- main fused kernel ----------------
// LDS: distT 256x32 f32 = 32 KB, cw_tile 32x256 f32 = 32 KB -> 64 KB -> 2 blocks/CU
__global__ __launch_bounds__(512, 4)
void hle_fused(const int*   __restrict__ ids,
               const float* __restrict__ fine_w,     // [VOCAB, HALF]
               const float* __restrict__ coarse_w,   // [NC, HALF]
               const float* __restrict__ cluster_w,  // [NC, VOCAB]
               const float* __restrict__ cluster_b,  // [NC]
               const int*   __restrict__ sorted,     // [NTOK] token order by id
               float*       __restrict__ out)        // [NTOK, 512]
{
    __shared__ float distT[NC][TPB];     // value for local slot t at distT[c][t ^ (c&28)]
    __shared__ float cw_tile[CK][HALF];

    const int tid  = threadIdx.x;
    const int wave = tid >> 6;   // 0..7
    const int lane = tid & 63;
    const int base = blockIdx.x * TPB;

    // ---------------- Phase 1: logits gather + softmax + fine gather ----------------
    {
        const int t0 = wave * 4;
        int tok[4], id[4];
#pragma unroll
        for (int i = 0; i < 4; ++i) {
            tok[i] = sorted[base + t0 + i];
            id[i]  = ids[tok[i]];
        }

        // fine rows: 64 lanes x float4 (coalesced 1KB per token)
        float4 f[4];
#pragma unroll
        for (int i = 0; i < 4; ++i)
            f[i] = *reinterpret_cast<const float4*>(fine_w + (size_t)id[i] * HALF + lane * 4);

        // scattered logit gather: 16 loads in flight per lane; sorted ids -> line reuse
        float lg[4][4];
#pragma unroll
        for (int i = 0; i < 4; ++i)
#pragma unroll
            for (int k = 0; k < 4; ++k)
                lg[i][k] = cluster_w[(size_t)(lane + 64 * k) * VOCAB + id[i]];

        float bias[4];
#pragma unroll
        for (int k = 0; k < 4; ++k) bias[k] = cluster_b[lane + 64 * k];

#pragma unroll
        for (int i = 0; i < 4; ++i) {
#pragma unroll
            for (int k = 0; k < 4; ++k) lg[i][k] += bias[k];

            float m = fmaxf(fmaxf(lg[i][0], lg[i][1]), fmaxf(lg[i][2], lg[i][3]));
#pragma unroll
            for (int off = 32; off >= 1; off >>= 1) m = fmaxf(m, __shfl_xor(m, off));
            float e[4], s = 0.f;
#pragma unroll
            for (int k = 0; k < 4; ++k) { e[k] = __expf(lg[i][k] - m); s += e[k]; }
#pragma unroll
            for (int off = 32; off >= 1; off >>= 1) s += __shfl_xor(s, off);
            const float inv = 1.f / s;

            const int t = t0 + i;
#pragma unroll
            for (int k = 0; k < 4; ++k) {
                const int c = lane + 64 * k;
                distT[c][t ^ (c & 28)] = e[k] * inv;
            }
            // fine half of output (row = original token)
            *reinterpret_cast<float4*>(out + (size_t)tok[i] * 512 + lane * 4) = f[i];
        }
    }

    // ---------------- Phase 2: coarse mixture, LDS-staged coarse_w ----------------
    float acc[4][4] = {{0.f}};
    const int tg4 = wave * 4;
    const int colbase = lane * 4;

    for (int ch = 0; ch < NC / CK; ++ch) {
        __syncthreads();
        {
            const float4* src = reinterpret_cast<const float4*>(coarse_w + (size_t)ch * CK * HALF);
            float4* dst = reinterpret_cast<float4*>(&cw_tile[0][0]);
#pragma unroll
            for (int p = 0; p < 4; ++p)
                dst[tid + p * 512] = src[tid + p * 512];
        }
        __syncthreads();

#pragma unroll 8
        for (int j = 0; j < CK; ++j) {
            const int cc = ch * CK + j;
            const float4 d = *reinterpret_cast<const float4*>(&distT[cc][tg4 ^ (cc & 28)]);
            const float4 v = *reinterpret_cast<const float4*>(&cw_tile[j][colbase]);
            acc[0][0] = fmaf(d.x, v.x, acc[0][0]);
            acc[0][1] = fmaf(d.x, v.y, acc[0][1]);
            acc[0][2] = fmaf(d.x, v.z, acc[0][2]);
            acc[0][3] = fmaf(d.x, v.w, acc[0][3]);
            acc[1][0] = fmaf(d.y, v.x, acc[1][0]);
            acc[1][1] = fmaf(d.y, v.y, acc[1][1]);
            acc[1][2] = fmaf(d.y, v.z, acc[1][2]);
            acc[1][3] = fmaf(d.y, v.w, acc[1][3]);
            acc[2][0] = fmaf(d.z, v.x, acc[2][0]);
            acc[2][1] = fmaf(d.z, v.y, acc[2][1]);
            acc[2][2] = fmaf(d.z, v.z, acc[2][2]);
            acc[2][3] = fmaf(d.z, v.w, acc[2][3]);
            acc[3][0] = fmaf(d.w, v.x, acc[3][0]);
            acc[3][1] = fmaf(d.w, v.y, acc[3][1]);
            acc[3][2] = fmaf(d.w, v.z, acc[3][2]);
            acc[3][3] = fmaf(d.w, v.w, acc[3][3]);
        }
    }

    // epilogue: coarse half of output at original token rows
#pragma unroll
    for (int jj = 0; jj < 4; ++jj) {
        const int tok = sorted[base + tg4 + jj];   // L1 hit
        float* o = out + (size_t)tok * 512 + 256 + colbase;
        *reinterpret_cast<float4*>(o) = make_float4(acc[jj][0], acc[jj][1], acc[jj][2], acc[jj][3]);
    }
}

extern "C" void kernel_launch(void* const* d_in, const int* in_sizes, int n_in,
                              void* d_out, int out_size, void* d_ws, size_t ws_size,
                              hipStream_t stream) {
    const int*   ids       = (const int*)  d_in[0];
    const float* fine_w    = (const float*)d_in[1];
    const float* coarse_w  = (const float*)d_in[2];
    const float* cluster_w = (const float*)d_in[3];
    const float* cluster_b = (const float*)d_in[4];
    float*       out       = (float*)d_out;

    int* offs   = (int*)d_ws;                 // [NBUCK]
    int* hist   = offs + NBUCK;               // [NBUCK]
    int* sorted = hist + NBUCK;               // [NTOK]

    hipMemsetAsync(hist, 0, NBUCK * sizeof(int), stream);
    hipLaunchKernelGGL(hist_kernel,    dim3(NTOK / 1024), dim3(1024), 0, stream, ids, hist);
    hipLaunchKernelGGL(scan_kernel,    dim3(1),           dim3(1024), 0, stream, hist, offs);
    hipLaunchKernelGGL(scatter_kernel, dim3(NTOK / 1024), dim3(1024), 0, stream, ids, offs, sorted);
    hipLaunchKernelGGL(hle_fused,      dim3(NTOK / TPB),  dim3(512),  0, stream,
                       ids, fine_w, coarse_w, cluster_w, cluster_b, sorted, out);
}

// Round 4
// 73.427 us; speedup vs baseline: 2.4009x; 1.1090x over previous
//
#include <hip/hip_runtime.h>

#define VOCAB 100000
#define HALF  256      // HIDDEN/2
#define NC    256      // NUM_CLUSTERS
#define NTOK  16384    // B*S
#define TPB   32       // tokens per block
#define CK    32       // cluster rows staged per chunk
#define NBUCK 2048     // id>>6 -> 0..1562, padded to 2048

// ---------------- sort prework ----------------
__global__ __launch_bounds__(1024)
void hist_kernel(const int* __restrict__ ids, int* __restrict__ hist) {
    const int t = blockIdx.x * 1024 + threadIdx.x;   // grid 16x1024 == NTOK
    atomicAdd(&hist[ids[t] >> 6], 1);
}

__global__ __launch_bounds__(1024)
void scan_kernel(const int* __restrict__ hist, int* __restrict__ offs) {
    __shared__ int part[1024];
    const int tid = threadIdx.x;
    const int h0 = hist[2 * tid], h1 = hist[2 * tid + 1];
    part[tid] = h0 + h1;
    __syncthreads();
    for (int off = 1; off < 1024; off <<= 1) {
        const int v   = part[tid];
        const int add = (tid >= off) ? part[tid - off] : 0;
        __syncthreads();
        part[tid] = v + add;
        __syncthreads();
    }
    const int excl = (tid == 0) ? 0 : part[tid - 1];
    offs[2 * tid]     = excl;
    offs[2 * tid + 1] = excl + h0;
}

__global__ __launch_bounds__(1024)
void scatter_kernel(const int* __restrict__ ids, int* __restrict__ offs,
                    int* __restrict__ sorted) {
    const int t = blockIdx.x * 1024 + threadIdx.x;
    const int pos = atomicAdd(&offs[ids[t] >> 6], 1);
    sorted[pos] = t;
}

// ---------------- main fused kernel ----------------
// LDS: distT 256x32 f32 = 32 KB, cw_tile 32x256 f32 = 32 KB -> 64 KB -> 2 blocks/CU
__global__ __launch_bounds__(512, 4)
void hle_fused(const int*   __restrict__ ids,
               const float* __restrict__ fine_w,     // [VOCAB, HALF]
               const float* __restrict__ coarse_w,   // [NC, HALF]
               const float* __restrict__ cluster_w,  // [NC, VOCAB]
               const float* __restrict__ cluster_b,  // [NC]
               const int*   __restrict__ sorted,     // [NTOK] token order by id
               float*       __restrict__ out)        // [NTOK, 512]
{
    __shared__ float distT[NC][TPB];     // value for local slot t at distT[c][t ^ (c&28)]
    __shared__ float cw_tile[CK][HALF];
    __shared__ int   sid_tok[TPB];
    __shared__ int   sid_id[TPB];

    const int tid  = threadIdx.x;
    const int wave = tid >> 6;   // 0..7
    const int lane = tid & 63;
    const int base = blockIdx.x * TPB;

    if (tid < TPB) {
        const int tok = sorted[base + tid];
        sid_tok[tid] = tok;
        sid_id[tid]  = ids[tok];
    }
    __syncthreads();

    // ---------------- Phase 1a: row-sliced logit gather ----------------
    // lane = (hi, token): 32 SORTED ids per row per instruction -> coalescer
    // merges to ~13 lines/row (gap 6.1 < 16/line). 16 independent loads in flight.
    {
        const int tl = lane & 31;       // local token slot
        const int hi = lane >> 5;       // row parity within wave pair
        const int id = sid_id[tl];
        const int c0 = 2 * wave + hi;   // rows c0 + 16k, k=0..15 cover 0..255

        float lg[16];
#pragma unroll
        for (int k = 0; k < 16; ++k)
            lg[k] = cluster_w[(size_t)(c0 + 16 * k) * VOCAB + id];

#pragma unroll
        for (int k = 0; k < 16; ++k) {
            const int c = c0 + 16 * k;
            distT[c][tl ^ (c & 28)] = lg[k] + cluster_b[c];   // conflict-free: bank = tl
        }
    }
    __syncthreads();

    // ---------------- Phase 1b: softmax (wave -> 4 tokens) + fine gather ----------------
    {
        const int t0 = wave * 4;
#pragma unroll
        for (int i = 0; i < 4; ++i) {
            const int t = t0 + i;
            float v[4];
#pragma unroll
            for (int k = 0; k < 4; ++k) {
                const int c = lane + 64 * k;
                v[k] = distT[c][t ^ (c & 28)];   // 4-way bank conflict (cheap)
            }
            float m = fmaxf(fmaxf(v[0], v[1]), fmaxf(v[2], v[3]));
#pragma unroll
            for (int off = 32; off >= 1; off >>= 1) m = fmaxf(m, __shfl_xor(m, off));
            float e[4], s = 0.f;
#pragma unroll
            for (int k = 0; k < 4; ++k) { e[k] = __expf(v[k] - m); s += e[k]; }
#pragma unroll
            for (int off = 32; off >= 1; off >>= 1) s += __shfl_xor(s, off);
            const float inv = 1.f / s;
#pragma unroll
            for (int k = 0; k < 4; ++k) {
                const int c = lane + 64 * k;
                distT[c][t ^ (c & 28)] = e[k] * inv;
            }
            // fine half of output (coalesced 1KB row per token)
            const int tok = sid_tok[t];
            const float4 f = *reinterpret_cast<const float4*>(
                fine_w + (size_t)sid_id[t] * HALF + lane * 4);
            *reinterpret_cast<float4*>(out + (size_t)tok * 512 + lane * 4) = f;
        }
    }

    // ---------------- Phase 2: coarse mixture, LDS-staged coarse_w ----------------
    float acc[4][4] = {{0.f}};
    const int tg4 = wave * 4;
    const int colbase = lane * 4;

    for (int ch = 0; ch < NC / CK; ++ch) {
        __syncthreads();   // prev chunk consumed (and, at ch=0, distT normalized)
        {
            const float4* src = reinterpret_cast<const float4*>(coarse_w + (size_t)ch * CK * HALF);
            float4* dst = reinterpret_cast<float4*>(&cw_tile[0][0]);
#pragma unroll
            for (int p = 0; p < 4; ++p)
                dst[tid + p * 512] = src[tid + p * 512];
        }
        __syncthreads();

#pragma unroll 8
        for (int j = 0; j < CK; ++j) {
            const int cc = ch * CK + j;
            const float4 d = *reinterpret_cast<const float4*>(&distT[cc][tg4 ^ (cc & 28)]); // broadcast
            const float4 v = *reinterpret_cast<const float4*>(&cw_tile[j][colbase]);        // contiguous
            acc[0][0] = fmaf(d.x, v.x, acc[0][0]);
            acc[0][1] = fmaf(d.x, v.y, acc[0][1]);
            acc[0][2] = fmaf(d.x, v.z, acc[0][2]);
            acc[0][3] = fmaf(d.x, v.w, acc[0][3]);
            acc[1][0] = fmaf(d.y, v.x, acc[1][0]);
            acc[1][1] = fmaf(d.y, v.y, acc[1][1]);
            acc[1][2] = fmaf(d.y, v.z, acc[1][2]);
            acc[1][3] = fmaf(d.y, v.w, acc[1][3]);
            acc[2][0] = fmaf(d.z, v.x, acc[2][0]);
            acc[2][1] = fmaf(d.z, v.y, acc[2][1]);
            acc[2][2] = fmaf(d.z, v.z, acc[2][2]);
            acc[2][3] = fmaf(d.z, v.w, acc[2][3]);
            acc[3][0] = fmaf(d.w, v.x, acc[3][0]);
            acc[3][1] = fmaf(d.w, v.y, acc[3][1]);
            acc[3][2] = fmaf(d.w, v.z, acc[3][2]);
            acc[3][3] = fmaf(d.w, v.w, acc[3][3]);
        }
    }

    // epilogue: coarse half of output at original token rows (1KB coalesced per token)
#pragma unroll
    for (int jj = 0; jj < 4; ++jj) {
        const int tok = sid_tok[tg4 + jj];
        float* o = out + (size_t)tok * 512 + 256 + colbase;
        *reinterpret_cast<float4*>(o) = make_float4(acc[jj][0], acc[jj][1], acc[jj][2], acc[jj][3]);
    }
}

extern "C" void kernel_launch(void* const* d_in, const int* in_sizes, int n_in,
                              void* d_out, int out_size, void* d_ws, size_t ws_size,
                              hipStream_t stream) {
    const int*   ids       = (const int*)  d_in[0];
    const float* fine_w    = (const float*)d_in[1];
    const float* coarse_w  = (const float*)d_in[2];
    const float* cluster_w = (const float*)d_in[3];
    const float* cluster_b = (const float*)d_in[4];
    float*       out       = (float*)d_out;

    int* offs   = (int*)d_ws;                 // [NBUCK]
    int* hist   = offs + NBUCK;               // [NBUCK]
    int* sorted = hist + NBUCK;               // [NTOK]

    hipMemsetAsync(hist, 0, NBUCK * sizeof(int), stream);
    hipLaunchKernelGGL(hist_kernel,    dim3(NTOK / 1024), dim3(1024), 0, stream, ids, hist);
    hipLaunchKernelGGL(scan_kernel,    dim3(1),           dim3(1024), 0, stream, hist, offs);
    hipLaunchKernelGGL(scatter_kernel, dim3(NTOK / 1024), dim3(1024), 0, stream, ids, offs, sorted);
    hipLaunchKernelGGL(hle_fused,      dim3(NTOK / TPB),  dim3(512),  0, stream,
                       ids, fine_w, coarse_w, cluster_w, cluster_b, sorted, out);
}